// Round 1
// baseline (5837.680 us; speedup 1.0000x reference)
//
#include <hip/hip_runtime.h>
#include <hip/hip_bf16.h>

typedef __hip_bfloat16 bf16;

#define Bz   4
#define Sz   320
#define FNz  64
#define Dz   256
#define HIDz 1024
#define TOK  (Bz*Sz*FNz)     // 81920 tokens
#define NSEQ (Bz*FNz)        // 256 column sequences
#define NTRz 256
#define NTEz 64
#define TTR  (NSEQ*NTRz)     // 65536 train tokens
#define TTE  (NSEQ*NTEz)     // 16384 test tokens
#define SCALE 0.17677669529663687f   // 1/sqrt(32)

// Map a "column-view" token rr (sequence-major) to its element offset in the
// row-layout (B,S,FN,D) tensor. Ls==0 -> plain contiguous rows of 256.
__device__ __forceinline__ size_t rowOff(int rr, int Ls, int s0){
  if (Ls == 0) return (size_t)rr * Dz;
  int n = rr / Ls;              // n = b*FN + f
  int s = rr - n * Ls + s0;
  return (((size_t)(n >> 6) * Sz + s) * FNz + (n & 63)) * Dz;
}

__device__ __forceinline__ void load8bf(const bf16* p, float* dst){
  uint4 raw = *(const uint4*)p;
  const bf16* b = (const bf16*)&raw;
  #pragma unroll
  for (int i = 0; i < 8; ++i) dst[i] = __bfloat162float(b[i]);
}

// ----------------- per-token LayerNorm stats (mu, rsqrt(var+eps)) -----------
__global__ __launch_bounds__(256) void stats_kernel(const float* __restrict__ src,
    float* __restrict__ mu, float* __restrict__ rs, int Ls, int s0){
  int rr   = blockIdx.x * 4 + (threadIdx.x >> 6);
  int lane = threadIdx.x & 63;
  size_t off = rowOff(rr, Ls, s0);
  float4 v = *(const float4*)(src + off + lane * 4);
  float s = v.x + v.y + v.z + v.w;
  float q = v.x*v.x + v.y*v.y + v.z*v.z + v.w*v.w;
  #pragma unroll
  for (int d = 1; d < 64; d <<= 1){ s += __shfl_xor(s, d); q += __shfl_xor(q, d); }
  if (lane == 0){
    float m   = s * (1.0f/Dz);
    float var = q * (1.0f/Dz) - m*m;
    mu[rr] = m;
    rs[rr] = rsqrtf(var + 1e-5f);
  }
}

// ----------------- generic tiled GEMM:  C = epi(A @ W^T + bias) -------------
// AKIND: 0 = f32 A (optionally LN-affine, optionally col-mapped rows)
//        1 = bf16 A (contiguous rows of length K)
// EPI:   0 = store bf16 (linear r*N+c)
//        1 = f32:  C[map] = resid[map] + v   (N must be 256 for mapping)
//        2 = store bf16 silu(v)
//        3 = store bf16 v * aux[r*N+c]
template<int AKIND, int LNA, int EPI>
__global__ __launch_bounds__(256) void gemm_kernel(
    const void* __restrict__ Ap, const float* __restrict__ W,
    const float* __restrict__ bias, void* __restrict__ Cp,
    const float* __restrict__ resid, const bf16* __restrict__ aux,
    const float* __restrict__ mu, const float* __restrict__ rs,
    const float* __restrict__ lng, const float* __restrict__ lnb,
    int M, int N, int K, int aLs, int aS0, int cLs, int cS0){
  __shared__ float As[64][33];
  __shared__ float Ws[64][33];
  const int tid  = threadIdx.x;
  const int r0   = blockIdx.y * 64;
  const int n0   = blockIdx.x * 64;
  const int lRow = tid >> 2;
  const int lK   = (tid & 3) * 8;
  size_t aOff;
  if (AKIND == 1) aOff = (size_t)(r0 + lRow) * K + lK;
  else            aOff = rowOff(r0 + lRow, aLs, aS0) + lK;
  const size_t wOff = (size_t)(n0 + lRow) * K + lK;
  float lmu = 0.f, lrs = 0.f;
  if (LNA){ lmu = mu[r0 + lRow]; lrs = rs[r0 + lRow]; }
  float acc[4][4] = {};
  for (int k0 = 0; k0 < K; k0 += 32){
    float av[8];
    if (AKIND == 0){
      const float* ap = (const float*)Ap + aOff + k0;
      float4 u0 = *(const float4*)ap;
      float4 u1 = *(const float4*)(ap + 4);
      av[0]=u0.x; av[1]=u0.y; av[2]=u0.z; av[3]=u0.w;
      av[4]=u1.x; av[5]=u1.y; av[6]=u1.z; av[7]=u1.w;
    } else {
      load8bf((const bf16*)Ap + aOff + k0, av);
    }
    if (LNA){
      #pragma unroll
      for (int i = 0; i < 8; ++i){
        int kg = k0 + lK + i;
        av[i] = (av[i] - lmu) * lrs * lng[kg] + lnb[kg];
      }
    }
    #pragma unroll
    for (int i = 0; i < 8; ++i) As[lRow][lK + i] = av[i];
    {
      const float* wp = W + wOff + k0;
      float4 w0 = *(const float4*)wp;
      float4 w1 = *(const float4*)(wp + 4);
      Ws[lRow][lK+0]=w0.x; Ws[lRow][lK+1]=w0.y; Ws[lRow][lK+2]=w0.z; Ws[lRow][lK+3]=w0.w;
      Ws[lRow][lK+4]=w1.x; Ws[lRow][lK+5]=w1.y; Ws[lRow][lK+6]=w1.z; Ws[lRow][lK+7]=w1.w;
    }
    __syncthreads();
    const int ty4 = (tid >> 4) << 2;
    const int tx4 = (tid & 15) << 2;
    #pragma unroll
    for (int kk = 0; kk < 32; ++kk){
      float a[4], wv[4];
      #pragma unroll
      for (int i = 0; i < 4; ++i) a[i]  = As[ty4 + i][kk];
      #pragma unroll
      for (int j = 0; j < 4; ++j) wv[j] = Ws[tx4 + j][kk];
      #pragma unroll
      for (int i = 0; i < 4; ++i)
        #pragma unroll
        for (int j = 0; j < 4; ++j) acc[i][j] += a[i] * wv[j];
    }
    __syncthreads();
  }
  const int ty4 = (tid >> 4) << 2;
  const int tx4 = (tid & 15) << 2;
  #pragma unroll
  for (int i = 0; i < 4; ++i){
    int r = r0 + ty4 + i;
    #pragma unroll
    for (int j = 0; j < 4; ++j){
      int c = n0 + tx4 + j;
      float v = acc[i][j] + bias[c];
      if (EPI == 0){
        ((bf16*)Cp)[(size_t)r * N + c] = __float2bfloat16(v);
      } else if (EPI == 1){
        size_t ro = rowOff(r, cLs, cS0) + c;
        ((float*)Cp)[ro] = resid[ro] + v;
      } else if (EPI == 2){
        float sv = v / (1.0f + __expf(-v));
        ((bf16*)Cp)[(size_t)r * N + c] = __float2bfloat16(sv);
      } else {
        float g = __bfloat162float(aux[(size_t)r * N + c]);
        ((bf16*)Cp)[(size_t)r * N + c] = __float2bfloat16(v * g);
      }
    }
  }
}

// ----------------- feature attention (Lq=Lk=64, hd=32, hybrid mask) ---------
__global__ __launch_bounds__(64) void attn_f_kernel(
    const bf16* __restrict__ Q, const bf16* __restrict__ K,
    const bf16* __restrict__ V, const float* __restrict__ mask,
    bf16* __restrict__ O){
  __shared__ float kh[64][32];
  __shared__ float vh[64][32];
  __shared__ float sc[64][65];
  const int r = blockIdx.x, h = blockIdx.y, t = threadIdx.x;
  const size_t base = (size_t)r * 64 * Dz + (size_t)h * 32;
  for (int dd = 0; dd < 32; dd += 8){
    load8bf(K + base + (size_t)t * Dz + dd, &kh[t][dd]);
    load8bf(V + base + (size_t)t * Dz + dd, &vh[t][dd]);
  }
  float qv[32];
  for (int dd = 0; dd < 32; dd += 8) load8bf(Q + base + (size_t)t * Dz + dd, &qv[dd]);
  __syncthreads();
  float m = -1e30f;
  for (int j = 0; j < 64; ++j){
    const float4* kr = (const float4*)kh[j];
    float s = 0.f;
    #pragma unroll
    for (int c = 0; c < 8; ++c){
      float4 kv = kr[c];
      s += qv[4*c]*kv.x + qv[4*c+1]*kv.y + qv[4*c+2]*kv.z + qv[4*c+3]*kv.w;
    }
    s *= SCALE;
    if (h < 4) s += (mask[t * 64 + j] == 1.0f ? 0.0f : -1e30f);
    sc[t][j] = s;
    m = fmaxf(m, s);
  }
  float l = 0.f;
  for (int j = 0; j < 64; ++j){ float p = __expf(sc[t][j] - m); sc[t][j] = p; l += p; }
  float inv = 1.0f / l;
  float accv[32];
  #pragma unroll
  for (int dd = 0; dd < 32; ++dd) accv[dd] = 0.f;
  for (int j = 0; j < 64; ++j){
    float p = sc[t][j];
    const float4* vr = (const float4*)vh[j];
    #pragma unroll
    for (int c = 0; c < 8; ++c){
      float4 vv = vr[c];
      accv[4*c]+=p*vv.x; accv[4*c+1]+=p*vv.y; accv[4*c+2]+=p*vv.z; accv[4*c+3]+=p*vv.w;
    }
  }
  for (int dd = 0; dd < 32; ++dd)
    O[base + (size_t)t * Dz + dd] = __float2bfloat16(accv[dd] * inv);
}

// ----------------- train self-attention (L=256, hd=32, no mask) ------------
__global__ __launch_bounds__(256) void attn_t_kernel(
    const bf16* __restrict__ Q, const bf16* __restrict__ K,
    const bf16* __restrict__ V, bf16* __restrict__ O){
  __shared__ float kh[256][32];
  __shared__ float vh[256][32];
  const int n = blockIdx.x, h = blockIdx.y, t = threadIdx.x;
  const size_t base = (size_t)n * 256 * Dz + (size_t)h * 32;
  for (int dd = 0; dd < 32; dd += 8){
    load8bf(K + base + (size_t)t * Dz + dd, &kh[t][dd]);
    load8bf(V + base + (size_t)t * Dz + dd, &vh[t][dd]);
  }
  float qv[32];
  for (int dd = 0; dd < 32; dd += 8) load8bf(Q + base + (size_t)t * Dz + dd, &qv[dd]);
  __syncthreads();
  float m = -1e30f;
  for (int j = 0; j < 256; ++j){
    const float4* kr = (const float4*)kh[j];
    float s = 0.f;
    #pragma unroll
    for (int c = 0; c < 8; ++c){
      float4 kv = kr[c];
      s += qv[4*c]*kv.x + qv[4*c+1]*kv.y + qv[4*c+2]*kv.z + qv[4*c+3]*kv.w;
    }
    m = fmaxf(m, s);
  }
  m *= SCALE;
  float l = 0.f;
  float accv[32];
  #pragma unroll
  for (int dd = 0; dd < 32; ++dd) accv[dd] = 0.f;
  for (int j = 0; j < 256; ++j){
    const float4* kr = (const float4*)kh[j];
    float s = 0.f;
    #pragma unroll
    for (int c = 0; c < 8; ++c){
      float4 kv = kr[c];
      s += qv[4*c]*kv.x + qv[4*c+1]*kv.y + qv[4*c+2]*kv.z + qv[4*c+3]*kv.w;
    }
    float p = __expf(s * SCALE - m);
    l += p;
    const float4* vr = (const float4*)vh[j];
    #pragma unroll
    for (int c = 0; c < 8; ++c){
      float4 vv = vr[c];
      accv[4*c]+=p*vv.x; accv[4*c+1]+=p*vv.y; accv[4*c+2]+=p*vv.z; accv[4*c+3]+=p*vv.w;
    }
  }
  float inv = 1.0f / l;
  for (int dd = 0; dd < 32; ++dd)
    O[base + (size_t)t * Dz + dd] = __float2bfloat16(accv[dd] * inv);
}

// ----------------- cross attention (Lq=64, Lk=256, hd=32) -------------------
__global__ __launch_bounds__(64) void attn_e_kernel(
    const bf16* __restrict__ Q, const bf16* __restrict__ K,
    const bf16* __restrict__ V, bf16* __restrict__ O){
  __shared__ float kh[256][32];
  __shared__ float vh[256][32];
  const int n = blockIdx.x, h = blockIdx.y, t = threadIdx.x;
  const size_t kbase = (size_t)n * 256 * Dz + (size_t)h * 32;
  for (int rr = t; rr < 256; rr += 64){
    for (int dd = 0; dd < 32; dd += 8){
      load8bf(K + kbase + (size_t)rr * Dz + dd, &kh[rr][dd]);
      load8bf(V + kbase + (size_t)rr * Dz + dd, &vh[rr][dd]);
    }
  }
  float qv[32];
  const size_t qbase = ((size_t)n * 64 + t) * Dz + (size_t)h * 32;
  for (int dd = 0; dd < 32; dd += 8) load8bf(Q + qbase + dd, &qv[dd]);
  __syncthreads();
  float m = -1e30f;
  for (int j = 0; j < 256; ++j){
    const float4* kr = (const float4*)kh[j];
    float s = 0.f;
    #pragma unroll
    for (int c = 0; c < 8; ++c){
      float4 kv = kr[c];
      s += qv[4*c]*kv.x + qv[4*c+1]*kv.y + qv[4*c+2]*kv.z + qv[4*c+3]*kv.w;
    }
    m = fmaxf(m, s);
  }
  m *= SCALE;
  float l = 0.f;
  float accv[32];
  #pragma unroll
  for (int dd = 0; dd < 32; ++dd) accv[dd] = 0.f;
  for (int j = 0; j < 256; ++j){
    const float4* kr = (const float4*)kh[j];
    float s = 0.f;
    #pragma unroll
    for (int c = 0; c < 8; ++c){
      float4 kv = kr[c];
      s += qv[4*c]*kv.x + qv[4*c+1]*kv.y + qv[4*c+2]*kv.z + qv[4*c+3]*kv.w;
    }
    float p = __expf(s * SCALE - m);
    l += p;
    const float4* vr = (const float4*)vh[j];
    #pragma unroll
    for (int c = 0; c < 8; ++c){
      float4 vv = vr[c];
      accv[4*c]+=p*vv.x; accv[4*c+1]+=p*vv.y; accv[4*c+2]+=p*vv.z; accv[4*c+3]+=p*vv.w;
    }
  }
  float inv = 1.0f / l;
  for (int dd = 0; dd < 32; ++dd)
    O[qbase + dd] = __float2bfloat16(accv[dd] * inv);
}

// ---------------------------------------------------------------------------
extern "C" void kernel_launch(void* const* d_in, const int* in_sizes, int n_in,
                              void* d_out, int out_size, void* d_ws, size_t ws_size,
                              hipStream_t stream){
  (void)in_sizes; (void)n_in; (void)out_size; (void)ws_size;
  const float* x    = (const float*)d_in[0];
  const float* mask = (const float*)d_in[1];
  const float *Wqf=(const float*)d_in[2],  *Wkf=(const float*)d_in[3],
              *Wvf=(const float*)d_in[4],  *Wof=(const float*)d_in[5],
              *bqf=(const float*)d_in[6],  *bkf=(const float*)d_in[7],
              *bvf=(const float*)d_in[8],  *bof=(const float*)d_in[9],
              *gf =(const float*)d_in[10], *b2f=(const float*)d_in[11];
  const float *Wqt=(const float*)d_in[12], *Wkt=(const float*)d_in[13],
              *Wvt=(const float*)d_in[14], *Wot=(const float*)d_in[15],
              *bqt=(const float*)d_in[16], *bkt=(const float*)d_in[17],
              *bvt=(const float*)d_in[18], *bot=(const float*)d_in[19],
              *gt =(const float*)d_in[20], *b2t=(const float*)d_in[21];
  const float *Wqe=(const float*)d_in[22], *Wke=(const float*)d_in[23],
              *Wve=(const float*)d_in[24], *Woe=(const float*)d_in[25],
              *bqe=(const float*)d_in[26], *bke=(const float*)d_in[27],
              *bve=(const float*)d_in[28], *boe=(const float*)d_in[29],
              *ge =(const float*)d_in[30], *b2e=(const float*)d_in[31];
  const float *W1=(const float*)d_in[32], *b1=(const float*)d_in[33],
              *Wg=(const float*)d_in[34], *bg=(const float*)d_in[35],
              *W2=(const float*)d_in[36], *b2v=(const float*)d_in[37],
              *gm=(const float*)d_in[38], *bm=(const float*)d_in[39];

  float* Y = (float*)d_out;     // running activation in row layout (B,S,FN,D)

  char* wsb = (char*)d_ws;
  size_t off = 0;
  auto carve = [&](size_t bytes)->void*{
    void* p = wsb + off; off += (bytes + 255) & ~(size_t)255; return p;
  };
  bf16* Qb = (bf16*)carve((size_t)TOK * Dz * 2);
  bf16* Kb = (bf16*)carve((size_t)TOK * Dz * 2);
  bf16* Vb = (bf16*)carve((size_t)TOK * Dz * 2);
  bf16* Ob = (bf16*)carve((size_t)TOK * Dz * 2);
  bf16* Gb = (bf16*)carve((size_t)8192 * HIDz * 2);
  bf16* Hb = (bf16*)carve((size_t)8192 * HIDz * 2);
  float* muA = (float*)carve((size_t)TOK*4); float* rsA = (float*)carve((size_t)TOK*4);
  float* muT = (float*)carve((size_t)TTR*4); float* rsT = (float*)carve((size_t)TTR*4);
  float* muK = (float*)carve((size_t)TTR*4); float* rsK = (float*)carve((size_t)TTR*4);
  float* muE = (float*)carve((size_t)TTE*4); float* rsE = (float*)carve((size_t)TTE*4);
  float* muM = (float*)carve((size_t)TOK*4); float* rsM = (float*)carve((size_t)TOK*4);

  // ---------------- Stage A: feature attention ----------------
  stats_kernel<<<TOK/4, 256, 0, stream>>>(x, muA, rsA, 0, 0);
  gemm_kernel<0,1,0><<<dim3(Dz/64, TOK/64), 256, 0, stream>>>(
      x, Wqf, bqf, Qb, nullptr, nullptr, muA, rsA, gf, b2f, TOK, Dz, Dz, 0,0,0,0);
  gemm_kernel<0,1,0><<<dim3(Dz/64, TOK/64), 256, 0, stream>>>(
      x, Wkf, bkf, Kb, nullptr, nullptr, muA, rsA, gf, b2f, TOK, Dz, Dz, 0,0,0,0);
  gemm_kernel<0,1,0><<<dim3(Dz/64, TOK/64), 256, 0, stream>>>(
      x, Wvf, bvf, Vb, nullptr, nullptr, muA, rsA, gf, b2f, TOK, Dz, Dz, 0,0,0,0);
  attn_f_kernel<<<dim3(Bz*Sz, 8), 64, 0, stream>>>(Qb, Kb, Vb, mask, Ob);
  gemm_kernel<1,0,1><<<dim3(Dz/64, TOK/64), 256, 0, stream>>>(
      Ob, Wof, bof, Y, x, nullptr, nullptr, nullptr, nullptr, nullptr,
      TOK, Dz, Dz, 0,0,0,0);

  // ---------------- Stage B: train self-attention ----------------
  stats_kernel<<<TTR/4, 256, 0, stream>>>(Y, muT, rsT, NTRz, 0);
  gemm_kernel<0,1,0><<<dim3(Dz/64, TTR/64), 256, 0, stream>>>(
      Y, Wqt, bqt, Qb, nullptr, nullptr, muT, rsT, gt, b2t, TTR, Dz, Dz, NTRz,0,0,0);
  gemm_kernel<0,1,0><<<dim3(Dz/64, TTR/64), 256, 0, stream>>>(
      Y, Wkt, bkt, Kb, nullptr, nullptr, muT, rsT, gt, b2t, TTR, Dz, Dz, NTRz,0,0,0);
  gemm_kernel<0,1,0><<<dim3(Dz/64, TTR/64), 256, 0, stream>>>(
      Y, Wvt, bvt, Vb, nullptr, nullptr, muT, rsT, gt, b2t, TTR, Dz, Dz, NTRz,0,0,0);
  attn_t_kernel<<<dim3(NSEQ, 8), 256, 0, stream>>>(Qb, Kb, Vb, Ob);
  gemm_kernel<1,0,1><<<dim3(Dz/64, TTR/64), 256, 0, stream>>>(
      Ob, Wot, bot, Y, Y, nullptr, nullptr, nullptr, nullptr, nullptr,
      TTR, Dz, Dz, 0,0, NTRz,0);

  // ---------------- Stage C: cross attention ----------------
  stats_kernel<<<TTR/4, 256, 0, stream>>>(Y, muK, rsK, NTRz, 0);
  stats_kernel<<<TTE/4, 256, 0, stream>>>(Y, muE, rsE, NTEz, NTRz);
  gemm_kernel<0,1,0><<<dim3(Dz/64, TTE/64), 256, 0, stream>>>(
      Y, Wqe, bqe, Qb, nullptr, nullptr, muE, rsE, ge, b2e, TTE, Dz, Dz, NTEz,NTRz,0,0);
  gemm_kernel<0,1,0><<<dim3(Dz/64, TTR/64), 256, 0, stream>>>(
      Y, Wke, bke, Kb, nullptr, nullptr, muK, rsK, ge, b2e, TTR, Dz, Dz, NTRz,0,0,0);
  gemm_kernel<0,1,0><<<dim3(Dz/64, TTR/64), 256, 0, stream>>>(
      Y, Wve, bve, Vb, nullptr, nullptr, muK, rsK, ge, b2e, TTR, Dz, Dz, NTRz,0,0,0);
  attn_e_kernel<<<dim3(NSEQ, 8), 64, 0, stream>>>(Qb, Kb, Vb, Ob);
  gemm_kernel<1,0,1><<<dim3(Dz/64, TTE/64), 256, 0, stream>>>(
      Ob, Woe, boe, Y, Y, nullptr, nullptr, nullptr, nullptr, nullptr,
      TTE, Dz, Dz, 0,0, NTEz,NTRz);

  // ---------------- Stage D: gated MLP ----------------
  stats_kernel<<<TOK/4, 256, 0, stream>>>(Y, muM, rsM, 0, 0);
  for (int c = 0; c < TOK/8192; ++c){
    const float* Yc = Y + (size_t)c * 8192 * Dz;
    float*       Yw = Y + (size_t)c * 8192 * Dz;
    const float* muc = muM + (size_t)c * 8192;
    const float* rsc = rsM + (size_t)c * 8192;
    gemm_kernel<0,1,2><<<dim3(HIDz/64, 8192/64), 256, 0, stream>>>(
        Yc, Wg, bg, Gb, nullptr, nullptr, muc, rsc, gm, bm, 8192, HIDz, Dz, 0,0,0,0);
    gemm_kernel<0,1,3><<<dim3(HIDz/64, 8192/64), 256, 0, stream>>>(
        Yc, W1, b1, Hb, nullptr, Gb, muc, rsc, gm, bm, 8192, HIDz, Dz, 0,0,0,0);
    gemm_kernel<1,0,1><<<dim3(Dz/64, 8192/64), 256, 0, stream>>>(
        Hb, W2, b2v, Yw, Yc, nullptr, nullptr, nullptr, nullptr, nullptr,
        8192, Dz, HIDz, 0,0,0,0);
  }
}

// Round 2
// 2123.004 us; speedup vs baseline: 2.7497x; 2.7497x over previous
//
#include <hip/hip_runtime.h>
#include <hip/hip_bf16.h>

typedef __hip_bfloat16 bf16;
typedef __attribute__((ext_vector_type(8))) short short8v;
typedef __attribute__((ext_vector_type(4))) float f32x4;

#define Bz   4
#define Sz   320
#define FNz  64
#define Dz   256
#define HIDz 1024
#define TOK  (Bz*Sz*FNz)     // 81920 tokens
#define NSEQ (Bz*FNz)        // 256 column sequences
#define NTRz 256
#define NTEz 64
#define TTR  (NSEQ*NTRz)     // 65536 train tokens
#define TTE  (NSEQ*NTEz)     // 16384 test tokens
#define SCALE 0.17677669529663687f   // 1/sqrt(32)

// Map a "column-view" token rr (sequence-major) to its element offset in the
// row-layout (B,S,FN,D) tensor. Ls==0 -> plain contiguous rows of 256.
__device__ __forceinline__ size_t rowOff(int rr, int Ls, int s0){
  if (Ls == 0) return (size_t)rr * Dz;
  int n = rr / Ls;              // n = b*FN + f
  int s = rr - n * Ls + s0;
  return (((size_t)(n >> 6) * Sz + s) * FNz + (n & 63)) * Dz;
}

__device__ __forceinline__ void load8bf(const bf16* p, float* dst){
  uint4 raw = *(const uint4*)p;
  const bf16* b = (const bf16*)&raw;
  #pragma unroll
  for (int i = 0; i < 8; ++i) dst[i] = __bfloat162float(b[i]);
}

__device__ __forceinline__ void store4bf(bf16* p, float a, float b, float c, float d){
  bf16 t0=__float2bfloat16(a), t1=__float2bfloat16(b),
       t2=__float2bfloat16(c), t3=__float2bfloat16(d);
  ushort4 u;
  u.x=*(unsigned short*)&t0; u.y=*(unsigned short*)&t1;
  u.z=*(unsigned short*)&t2; u.w=*(unsigned short*)&t3;
  *(ushort4*)p = u;
}

// ----------------- f32 -> bf16 weight conversion ---------------------------
__global__ __launch_bounds__(256) void cvt_kernel(const float* __restrict__ src,
    bf16* __restrict__ dst, int n){
  int i = (blockIdx.x * 256 + threadIdx.x) * 4;
  if (i >= n) return;
  float4 v = *(const float4*)(src + i);
  store4bf(dst + i, v.x, v.y, v.z, v.w);
}

// ----------------- fused LayerNorm -> contiguous bf16 rows ------------------
// Reads (optionally column-view strided) f32 rows, writes dst[rr*256 + d] bf16.
__global__ __launch_bounds__(256) void ln_kernel(const float* __restrict__ src,
    bf16* __restrict__ dst, const float* __restrict__ g, const float* __restrict__ b,
    int Ls, int s0){
  int rr   = blockIdx.x * 4 + (threadIdx.x >> 6);
  int lane = threadIdx.x & 63;
  size_t off = rowOff(rr, Ls, s0) + (size_t)lane * 4;
  float4 v = *(const float4*)(src + off);
  float s = v.x + v.y + v.z + v.w;
  float q = v.x*v.x + v.y*v.y + v.z*v.z + v.w*v.w;
  #pragma unroll
  for (int d = 1; d < 64; d <<= 1){ s += __shfl_xor(s, d); q += __shfl_xor(q, d); }
  float m   = s * (1.0f/Dz);
  float rsd = rsqrtf(q * (1.0f/Dz) - m*m + 1e-5f);
  float4 gv = *(const float4*)(g + lane*4);
  float4 bv = *(const float4*)(b + lane*4);
  store4bf(dst + (size_t)rr*Dz + lane*4,
           (v.x-m)*rsd*gv.x + bv.x, (v.y-m)*rsd*gv.y + bv.y,
           (v.z-m)*rsd*gv.z + bv.z, (v.w-m)*rsd*gv.w + bv.w);
}

// ----------------- MFMA bf16 GEMM:  C = epi(A @ W^T + bias) ----------------
// A: bf16 [M x K] contiguous rows.  Wb: bf16 [N x K] (i.e. B^T).
// EPI: 0 = store bf16 (r*N+c)
//      1 = f32: C[rowOff(r)] = resid[rowOff(r)] + v
//      2 = store bf16 silu(v)
//      3 = store bf16 v * aux[r*N+c]
template<int EPI>
__global__ __launch_bounds__(256) void mgemm(
    const bf16* __restrict__ A, const bf16* __restrict__ Wb,
    const float* __restrict__ bias, void* __restrict__ Cp,
    const float* __restrict__ resid, const bf16* __restrict__ aux,
    int M, int N, int K, int cLs, int cS0){
  __shared__ bf16 As[128][40];   // +8 pad: conflict-free ds_read_b128
  __shared__ bf16 Bs[128][40];
  const int tid  = threadIdx.x;
  const int lane = tid & 63;
  const int wave = tid >> 6;
  const int r0 = blockIdx.y * 128;
  const int n0 = blockIdx.x * 128;
  // staging: each thread loads 16 elems of A-tile and 16 of B-tile per K-step
  const int srow = tid >> 1;           // 0..127
  const int scol = (tid & 1) * 16;     // 0 or 16
  const bf16* ap = A  + (size_t)(r0 + srow) * K + scol;
  const bf16* bp = Wb + (size_t)(n0 + srow) * K + scol;
  // wave tile: 64x64 at (wr*64, wc*64)
  const int wr = wave >> 1, wc = wave & 1;
  const int fr = lane & 15;            // fragment row (A) / col (B)
  const int fk = (lane >> 4) * 8;      // fragment k-offset
  f32x4 acc[4][4] = {};
  for (int k0 = 0; k0 < K; k0 += 32){
    uint4 a0 = *(const uint4*)(ap + k0);
    uint4 a1 = *(const uint4*)(ap + k0 + 8);
    uint4 b0 = *(const uint4*)(bp + k0);
    uint4 b1 = *(const uint4*)(bp + k0 + 8);
    __syncthreads();
    *(uint4*)&As[srow][scol]     = a0;
    *(uint4*)&As[srow][scol + 8] = a1;
    *(uint4*)&Bs[srow][scol]     = b0;
    *(uint4*)&Bs[srow][scol + 8] = b1;
    __syncthreads();
    short8v af[4], bf[4];
    #pragma unroll
    for (int m = 0; m < 4; ++m)
      af[m] = *(const short8v*)&As[wr*64 + m*16 + fr][fk];
    #pragma unroll
    for (int n = 0; n < 4; ++n)
      bf[n] = *(const short8v*)&Bs[wc*64 + n*16 + fr][fk];
    #pragma unroll
    for (int m = 0; m < 4; ++m)
      #pragma unroll
      for (int n = 0; n < 4; ++n)
        acc[m][n] = __builtin_amdgcn_mfma_f32_16x16x32_bf16(af[m], bf[n], acc[m][n], 0, 0, 0);
  }
  // epilogue: lane holds C[r0+wr*64+m*16+(lane>>4)*4+j][n0+wc*64+n*16+(lane&15)]
  const int er = (lane >> 4) * 4;
  #pragma unroll
  for (int m = 0; m < 4; ++m){
    #pragma unroll
    for (int j = 0; j < 4; ++j){
      int r = r0 + wr*64 + m*16 + er + j;
      #pragma unroll
      for (int n = 0; n < 4; ++n){
        int c = n0 + wc*64 + n*16 + fr;
        float v = acc[m][n][j] + bias[c];
        if (EPI == 0){
          ((bf16*)Cp)[(size_t)r * N + c] = __float2bfloat16(v);
        } else if (EPI == 1){
          size_t ro = rowOff(r, cLs, cS0) + c;
          ((float*)Cp)[ro] = resid[ro] + v;
        } else if (EPI == 2){
          float sv = v / (1.0f + __expf(-v));
          ((bf16*)Cp)[(size_t)r * N + c] = __float2bfloat16(sv);
        } else {
          float gg = __bfloat162float(aux[(size_t)r * N + c]);
          ((bf16*)Cp)[(size_t)r * N + c] = __float2bfloat16(v * gg);
        }
      }
    }
  }
}

// ----------------- feature attention (Lq=Lk=64, hd=32, hybrid mask) ---------
__global__ __launch_bounds__(64) void attn_f_kernel(
    const bf16* __restrict__ Q, const bf16* __restrict__ K,
    const bf16* __restrict__ V, const float* __restrict__ mask,
    bf16* __restrict__ O){
  __shared__ float kh[64][32];
  __shared__ float vh[64][32];
  __shared__ float sc[64][65];
  const int r = blockIdx.x, h = blockIdx.y, t = threadIdx.x;
  const size_t base = (size_t)r * 64 * Dz + (size_t)h * 32;
  for (int dd = 0; dd < 32; dd += 8){
    load8bf(K + base + (size_t)t * Dz + dd, &kh[t][dd]);
    load8bf(V + base + (size_t)t * Dz + dd, &vh[t][dd]);
  }
  float qv[32];
  for (int dd = 0; dd < 32; dd += 8) load8bf(Q + base + (size_t)t * Dz + dd, &qv[dd]);
  __syncthreads();
  float m = -1e30f;
  for (int j = 0; j < 64; ++j){
    const float4* kr = (const float4*)kh[j];
    float s = 0.f;
    #pragma unroll
    for (int c = 0; c < 8; ++c){
      float4 kv = kr[c];
      s += qv[4*c]*kv.x + qv[4*c+1]*kv.y + qv[4*c+2]*kv.z + qv[4*c+3]*kv.w;
    }
    s *= SCALE;
    if (h < 4) s += (mask[t * 64 + j] == 1.0f ? 0.0f : -1e30f);
    sc[t][j] = s;
    m = fmaxf(m, s);
  }
  float l = 0.f;
  for (int j = 0; j < 64; ++j){ float p = __expf(sc[t][j] - m); sc[t][j] = p; l += p; }
  float inv = 1.0f / l;
  float accv[32];
  #pragma unroll
  for (int dd = 0; dd < 32; ++dd) accv[dd] = 0.f;
  for (int j = 0; j < 64; ++j){
    float p = sc[t][j];
    const float4* vr = (const float4*)vh[j];
    #pragma unroll
    for (int c = 0; c < 8; ++c){
      float4 vv = vr[c];
      accv[4*c]+=p*vv.x; accv[4*c+1]+=p*vv.y; accv[4*c+2]+=p*vv.z; accv[4*c+3]+=p*vv.w;
    }
  }
  for (int dd = 0; dd < 32; ++dd)
    O[base + (size_t)t * Dz + dd] = __float2bfloat16(accv[dd] * inv);
}

// ----------------- train self-attention (L=256, hd=32, no mask) ------------
__global__ __launch_bounds__(256) void attn_t_kernel(
    const bf16* __restrict__ Q, const bf16* __restrict__ K,
    const bf16* __restrict__ V, bf16* __restrict__ O){
  __shared__ float kh[256][32];
  __shared__ float vh[256][32];
  const int n = blockIdx.x, h = blockIdx.y, t = threadIdx.x;
  const size_t base = (size_t)n * 256 * Dz + (size_t)h * 32;
  for (int dd = 0; dd < 32; dd += 8){
    load8bf(K + base + (size_t)t * Dz + dd, &kh[t][dd]);
    load8bf(V + base + (size_t)t * Dz + dd, &vh[t][dd]);
  }
  float qv[32];
  for (int dd = 0; dd < 32; dd += 8) load8bf(Q + base + (size_t)t * Dz + dd, &qv[dd]);
  __syncthreads();
  float m = -1e30f;
  for (int j = 0; j < 256; ++j){
    const float4* kr = (const float4*)kh[j];
    float s = 0.f;
    #pragma unroll
    for (int c = 0; c < 8; ++c){
      float4 kv = kr[c];
      s += qv[4*c]*kv.x + qv[4*c+1]*kv.y + qv[4*c+2]*kv.z + qv[4*c+3]*kv.w;
    }
    m = fmaxf(m, s);
  }
  m *= SCALE;
  float l = 0.f;
  float accv[32];
  #pragma unroll
  for (int dd = 0; dd < 32; ++dd) accv[dd] = 0.f;
  for (int j = 0; j < 256; ++j){
    const float4* kr = (const float4*)kh[j];
    float s = 0.f;
    #pragma unroll
    for (int c = 0; c < 8; ++c){
      float4 kv = kr[c];
      s += qv[4*c]*kv.x + qv[4*c+1]*kv.y + qv[4*c+2]*kv.z + qv[4*c+3]*kv.w;
    }
    float p = __expf(s * SCALE - m);
    l += p;
    const float4* vr = (const float4*)vh[j];
    #pragma unroll
    for (int c = 0; c < 8; ++c){
      float4 vv = vr[c];
      accv[4*c]+=p*vv.x; accv[4*c+1]+=p*vv.y; accv[4*c+2]+=p*vv.z; accv[4*c+3]+=p*vv.w;
    }
  }
  float inv = 1.0f / l;
  for (int dd = 0; dd < 32; ++dd)
    O[base + (size_t)t * Dz + dd] = __float2bfloat16(accv[dd] * inv);
}

// ----------------- cross attention (Lq=64, Lk=256, hd=32) -------------------
__global__ __launch_bounds__(64) void attn_e_kernel(
    const bf16* __restrict__ Q, const bf16* __restrict__ K,
    const bf16* __restrict__ V, bf16* __restrict__ O){
  __shared__ float kh[256][32];
  __shared__ float vh[256][32];
  const int n = blockIdx.x, h = blockIdx.y, t = threadIdx.x;
  const size_t kbase = (size_t)n * 256 * Dz + (size_t)h * 32;
  for (int rr = t; rr < 256; rr += 64){
    for (int dd = 0; dd < 32; dd += 8){
      load8bf(K + kbase + (size_t)rr * Dz + dd, &kh[rr][dd]);
      load8bf(V + kbase + (size_t)rr * Dz + dd, &vh[rr][dd]);
    }
  }
  float qv[32];
  const size_t qbase = ((size_t)n * 64 + t) * Dz + (size_t)h * 32;
  for (int dd = 0; dd < 32; dd += 8) load8bf(Q + qbase + dd, &qv[dd]);
  __syncthreads();
  float m = -1e30f;
  for (int j = 0; j < 256; ++j){
    const float4* kr = (const float4*)kh[j];
    float s = 0.f;
    #pragma unroll
    for (int c = 0; c < 8; ++c){
      float4 kv = kr[c];
      s += qv[4*c]*kv.x + qv[4*c+1]*kv.y + qv[4*c+2]*kv.z + qv[4*c+3]*kv.w;
    }
    m = fmaxf(m, s);
  }
  m *= SCALE;
  float l = 0.f;
  float accv[32];
  #pragma unroll
  for (int dd = 0; dd < 32; ++dd) accv[dd] = 0.f;
  for (int j = 0; j < 256; ++j){
    const float4* kr = (const float4*)kh[j];
    float s = 0.f;
    #pragma unroll
    for (int c = 0; c < 8; ++c){
      float4 kv = kr[c];
      s += qv[4*c]*kv.x + qv[4*c+1]*kv.y + qv[4*c+2]*kv.z + qv[4*c+3]*kv.w;
    }
    float p = __expf(s * SCALE - m);
    l += p;
    const float4* vr = (const float4*)vh[j];
    #pragma unroll
    for (int c = 0; c < 8; ++c){
      float4 vv = vr[c];
      accv[4*c]+=p*vv.x; accv[4*c+1]+=p*vv.y; accv[4*c+2]+=p*vv.z; accv[4*c+3]+=p*vv.w;
    }
  }
  float inv = 1.0f / l;
  for (int dd = 0; dd < 32; ++dd)
    O[qbase + dd] = __float2bfloat16(accv[dd] * inv);
}

// ---------------------------------------------------------------------------
extern "C" void kernel_launch(void* const* d_in, const int* in_sizes, int n_in,
                              void* d_out, int out_size, void* d_ws, size_t ws_size,
                              hipStream_t stream){
  (void)in_sizes; (void)n_in; (void)out_size; (void)ws_size;
  const float* x    = (const float*)d_in[0];
  const float* mask = (const float*)d_in[1];
  const float *Wqf=(const float*)d_in[2],  *Wkf=(const float*)d_in[3],
              *Wvf=(const float*)d_in[4],  *Wof=(const float*)d_in[5],
              *bqf=(const float*)d_in[6],  *bkf=(const float*)d_in[7],
              *bvf=(const float*)d_in[8],  *bof=(const float*)d_in[9],
              *gf =(const float*)d_in[10], *b2f=(const float*)d_in[11];
  const float *Wqt=(const float*)d_in[12], *Wkt=(const float*)d_in[13],
              *Wvt=(const float*)d_in[14], *Wot=(const float*)d_in[15],
              *bqt=(const float*)d_in[16], *bkt=(const float*)d_in[17],
              *bvt=(const float*)d_in[18], *bot=(const float*)d_in[19],
              *gt =(const float*)d_in[20], *b2t=(const float*)d_in[21];
  const float *Wqe=(const float*)d_in[22], *Wke=(const float*)d_in[23],
              *Wve=(const float*)d_in[24], *Woe=(const float*)d_in[25],
              *bqe=(const float*)d_in[26], *bke=(const float*)d_in[27],
              *bve=(const float*)d_in[28], *boe=(const float*)d_in[29],
              *ge =(const float*)d_in[30], *b2e=(const float*)d_in[31];
  const float *W1=(const float*)d_in[32], *b1=(const float*)d_in[33],
              *Wg=(const float*)d_in[34], *bg=(const float*)d_in[35],
              *W2=(const float*)d_in[36], *b2v=(const float*)d_in[37],
              *gm=(const float*)d_in[38], *bm=(const float*)d_in[39];

  float* Y = (float*)d_out;     // running activation in row layout (B,S,FN,D)

  char* wsb = (char*)d_ws;
  size_t off = 0;
  auto carve = [&](size_t bytes)->void*{
    void* p = wsb + off; off += (bytes + 255) & ~(size_t)255; return p;
  };
  bf16* Xn = (bf16*)carve((size_t)TOK * Dz * 2);   // LN'd activations (contiguous)
  bf16* Qb = (bf16*)carve((size_t)TOK * Dz * 2);
  bf16* Kb = (bf16*)carve((size_t)TOK * Dz * 2);
  bf16* Vb = (bf16*)carve((size_t)TOK * Dz * 2);
  bf16* Ob = (bf16*)carve((size_t)TOK * Dz * 2);
  // bf16 weights
  bf16 *wb[15];
  const float* wsrc[15] = {Wqf,Wkf,Wvf,Wof, Wqt,Wkt,Wvt,Wot, Wqe,Wke,Wve,Woe, W1,Wg,W2};
  const int    wn[15]   = {Dz*Dz,Dz*Dz,Dz*Dz,Dz*Dz, Dz*Dz,Dz*Dz,Dz*Dz,Dz*Dz,
                           Dz*Dz,Dz*Dz,Dz*Dz,Dz*Dz, HIDz*Dz,HIDz*Dz,HIDz*Dz};
  for (int i = 0; i < 15; ++i) wb[i] = (bf16*)carve((size_t)wn[i]*2);
  for (int i = 0; i < 15; ++i)
    cvt_kernel<<<wn[i]/1024, 256, 0, stream>>>(wsrc[i], wb[i], wn[i]);
  bf16 *Wqfb=wb[0],*Wkfb=wb[1],*Wvfb=wb[2],*Wofb=wb[3],
       *Wqtb=wb[4],*Wktb=wb[5],*Wvtb=wb[6],*Wotb=wb[7],
       *Wqeb=wb[8],*Wkeb=wb[9],*Wveb=wb[10],*Woeb=wb[11],
       *W1b=wb[12],*Wgb=wb[13],*W2b=wb[14];
  // MLP buffers alias Qb/Vb (attention finished by then); chunk = 16384 tokens
  bf16* Gb = Qb;
  bf16* Hb = Vb;

  // ---------------- Stage A: feature attention ----------------
  ln_kernel<<<TOK/4, 256, 0, stream>>>(x, Xn, gf, b2f, 0, 0);
  mgemm<0><<<dim3(2, TOK/128), 256, 0, stream>>>(Xn, Wqfb, bqf, Qb, nullptr, nullptr, TOK, Dz, Dz, 0,0);
  mgemm<0><<<dim3(2, TOK/128), 256, 0, stream>>>(Xn, Wkfb, bkf, Kb, nullptr, nullptr, TOK, Dz, Dz, 0,0);
  mgemm<0><<<dim3(2, TOK/128), 256, 0, stream>>>(Xn, Wvfb, bvf, Vb, nullptr, nullptr, TOK, Dz, Dz, 0,0);
  attn_f_kernel<<<dim3(Bz*Sz, 8), 64, 0, stream>>>(Qb, Kb, Vb, mask, Ob);
  mgemm<1><<<dim3(2, TOK/128), 256, 0, stream>>>(Ob, Wofb, bof, Y, x, nullptr, TOK, Dz, Dz, 0,0);

  // ---------------- Stage B: train self-attention ----------------
  ln_kernel<<<TTR/4, 256, 0, stream>>>(Y, Xn, gt, b2t, NTRz, 0);
  mgemm<0><<<dim3(2, TTR/128), 256, 0, stream>>>(Xn, Wqtb, bqt, Qb, nullptr, nullptr, TTR, Dz, Dz, 0,0);
  mgemm<0><<<dim3(2, TTR/128), 256, 0, stream>>>(Xn, Wktb, bkt, Kb, nullptr, nullptr, TTR, Dz, Dz, 0,0);
  mgemm<0><<<dim3(2, TTR/128), 256, 0, stream>>>(Xn, Wvtb, bvt, Vb, nullptr, nullptr, TTR, Dz, Dz, 0,0);
  attn_t_kernel<<<dim3(NSEQ, 8), 256, 0, stream>>>(Qb, Kb, Vb, Ob);
  mgemm<1><<<dim3(2, TTR/128), 256, 0, stream>>>(Ob, Wotb, bot, Y, Y, nullptr, TTR, Dz, Dz, NTRz,0);

  // ---------------- Stage C: cross attention ----------------
  ln_kernel<<<TTR/4, 256, 0, stream>>>(Y, Xn, ge, b2e, NTRz, 0);                 // kv rows
  ln_kernel<<<TTE/4, 256, 0, stream>>>(Y, Xn + (size_t)TTR*Dz, ge, b2e, NTEz, NTRz); // query rows
  mgemm<0><<<dim3(2, TTE/128), 256, 0, stream>>>(Xn + (size_t)TTR*Dz, Wqeb, bqe, Qb, nullptr, nullptr, TTE, Dz, Dz, 0,0);
  mgemm<0><<<dim3(2, TTR/128), 256, 0, stream>>>(Xn, Wkeb, bke, Kb, nullptr, nullptr, TTR, Dz, Dz, 0,0);
  mgemm<0><<<dim3(2, TTR/128), 256, 0, stream>>>(Xn, Wveb, bve, Vb, nullptr, nullptr, TTR, Dz, Dz, 0,0);
  attn_e_kernel<<<dim3(NSEQ, 8), 64, 0, stream>>>(Qb, Kb, Vb, Ob);
  mgemm<1><<<dim3(2, TTE/128), 256, 0, stream>>>(Ob, Woeb, boe, Y, Y, nullptr, TTE, Dz, Dz, NTEz,NTRz);

  // ---------------- Stage D: gated MLP ----------------
  ln_kernel<<<TOK/4, 256, 0, stream>>>(Y, Xn, gm, bm, 0, 0);
  for (int c = 0; c < TOK/16384; ++c){
    const bf16* Anc = Xn + (size_t)c * 16384 * Dz;
    float*      Yc  = Y  + (size_t)c * 16384 * Dz;
    mgemm<2><<<dim3(HIDz/128, 16384/128), 256, 0, stream>>>(Anc, Wgb, bg, Gb, nullptr, nullptr, 16384, HIDz, Dz, 0,0);
    mgemm<3><<<dim3(HIDz/128, 16384/128), 256, 0, stream>>>(Anc, W1b, b1, Hb, nullptr, Gb, 16384, HIDz, Dz, 0,0);
    mgemm<1><<<dim3(2, 16384/128), 256, 0, stream>>>(Hb, W2b, b2v, Yc, Yc, nullptr, 16384, Dz, HIDz, 0,0);
  }
}

// Round 3
// 1271.757 us; speedup vs baseline: 4.5902x; 1.6693x over previous
//
#include <hip/hip_runtime.h>
#include <hip/hip_bf16.h>

typedef __hip_bfloat16 bf16;
typedef __attribute__((ext_vector_type(8))) short short8v;
typedef __attribute__((ext_vector_type(4))) float f32x4;

#define Bz   4
#define Sz   320
#define FNz  64
#define Dz   256
#define HIDz 1024
#define TOK  (Bz*Sz*FNz)     // 81920 tokens
#define NSEQ (Bz*FNz)        // 256 column sequences
#define NTRz 256
#define NTEz 64
#define TTR  (NSEQ*NTRz)     // 65536 train tokens
#define TTE  (NSEQ*NTEz)     // 16384 test tokens
#define SCALE 0.17677669529663687f   // 1/sqrt(32)

// Map a "column-view" token rr (sequence-major) to its element offset in the
// row-layout (B,S,FN,D) tensor. Ls==0 -> plain contiguous rows of 256.
__device__ __forceinline__ size_t rowOff(int rr, int Ls, int s0){
  if (Ls == 0) return (size_t)rr * Dz;
  int n = rr / Ls;              // n = b*FN + f
  int s = rr - n * Ls + s0;
  return (((size_t)(n >> 6) * Sz + s) * FNz + (n & 63)) * Dz;
}

__device__ __forceinline__ void store4bf(bf16* p, float a, float b, float c, float d){
  bf16 t0=__float2bfloat16(a), t1=__float2bfloat16(b),
       t2=__float2bfloat16(c), t3=__float2bfloat16(d);
  ushort4 u;
  u.x=*(unsigned short*)&t0; u.y=*(unsigned short*)&t1;
  u.z=*(unsigned short*)&t2; u.w=*(unsigned short*)&t3;
  *(ushort4*)p = u;
}

// ----------------- f32 -> bf16 weight conversion ---------------------------
__global__ __launch_bounds__(256) void cvt_kernel(const float* __restrict__ src,
    bf16* __restrict__ dst, int n){
  int i = (blockIdx.x * 256 + threadIdx.x) * 4;
  if (i >= n) return;
  float4 v = *(const float4*)(src + i);
  store4bf(dst + i, v.x, v.y, v.z, v.w);
}

// ----------------- fused LayerNorm -> contiguous bf16 rows ------------------
__global__ __launch_bounds__(256) void ln_kernel(const float* __restrict__ src,
    bf16* __restrict__ dst, const float* __restrict__ g, const float* __restrict__ b,
    int Ls, int s0){
  int rr   = blockIdx.x * 4 + (threadIdx.x >> 6);
  int lane = threadIdx.x & 63;
  size_t off = rowOff(rr, Ls, s0) + (size_t)lane * 4;
  float4 v = *(const float4*)(src + off);
  float s = v.x + v.y + v.z + v.w;
  float q = v.x*v.x + v.y*v.y + v.z*v.z + v.w*v.w;
  #pragma unroll
  for (int d = 1; d < 64; d <<= 1){ s += __shfl_xor(s, d); q += __shfl_xor(q, d); }
  float m   = s * (1.0f/Dz);
  float rsd = rsqrtf(q * (1.0f/Dz) - m*m + 1e-5f);
  float4 gv = *(const float4*)(g + lane*4);
  float4 bv = *(const float4*)(b + lane*4);
  store4bf(dst + (size_t)rr*Dz + lane*4,
           (v.x-m)*rsd*gv.x + bv.x, (v.y-m)*rsd*gv.y + bv.y,
           (v.z-m)*rsd*gv.z + bv.z, (v.w-m)*rsd*gv.w + bv.w);
}

// ----------------- MFMA bf16 GEMM:  C = epi(A @ W^T + bias) ----------------
template<int EPI>
__global__ __launch_bounds__(256) void mgemm(
    const bf16* __restrict__ A, const bf16* __restrict__ Wb,
    const float* __restrict__ bias, void* __restrict__ Cp,
    const float* __restrict__ resid, const bf16* __restrict__ aux,
    int M, int N, int K, int cLs, int cS0){
  __shared__ bf16 As[128][40];
  __shared__ bf16 Bs[128][40];
  const int tid  = threadIdx.x;
  const int lane = tid & 63;
  const int wave = tid >> 6;
  const int r0 = blockIdx.y * 128;
  const int n0 = blockIdx.x * 128;
  const int srow = tid >> 1;
  const int scol = (tid & 1) * 16;
  const bf16* ap = A  + (size_t)(r0 + srow) * K + scol;
  const bf16* bp = Wb + (size_t)(n0 + srow) * K + scol;
  const int wr = wave >> 1, wc = wave & 1;
  const int fr = lane & 15;
  const int fk = (lane >> 4) * 8;
  f32x4 acc[4][4] = {};
  for (int k0 = 0; k0 < K; k0 += 32){
    uint4 a0 = *(const uint4*)(ap + k0);
    uint4 a1 = *(const uint4*)(ap + k0 + 8);
    uint4 b0 = *(const uint4*)(bp + k0);
    uint4 b1 = *(const uint4*)(bp + k0 + 8);
    __syncthreads();
    *(uint4*)&As[srow][scol]     = a0;
    *(uint4*)&As[srow][scol + 8] = a1;
    *(uint4*)&Bs[srow][scol]     = b0;
    *(uint4*)&Bs[srow][scol + 8] = b1;
    __syncthreads();
    short8v af[4], bf[4];
    #pragma unroll
    for (int m = 0; m < 4; ++m)
      af[m] = *(const short8v*)&As[wr*64 + m*16 + fr][fk];
    #pragma unroll
    for (int n = 0; n < 4; ++n)
      bf[n] = *(const short8v*)&Bs[wc*64 + n*16 + fr][fk];
    #pragma unroll
    for (int m = 0; m < 4; ++m)
      #pragma unroll
      for (int n = 0; n < 4; ++n)
        acc[m][n] = __builtin_amdgcn_mfma_f32_16x16x32_bf16(af[m], bf[n], acc[m][n], 0, 0, 0);
  }
  const int er = (lane >> 4) * 4;
  #pragma unroll
  for (int m = 0; m < 4; ++m){
    #pragma unroll
    for (int j = 0; j < 4; ++j){
      int r = r0 + wr*64 + m*16 + er + j;
      #pragma unroll
      for (int n = 0; n < 4; ++n){
        int c = n0 + wc*64 + n*16 + fr;
        float v = acc[m][n][j] + bias[c];
        if (EPI == 0){
          ((bf16*)Cp)[(size_t)r * N + c] = __float2bfloat16(v);
        } else if (EPI == 1){
          size_t ro = rowOff(r, cLs, cS0) + c;
          ((float*)Cp)[ro] = resid[ro] + v;
        } else if (EPI == 2){
          float sv = v / (1.0f + __expf(-v));
          ((bf16*)Cp)[(size_t)r * N + c] = __float2bfloat16(sv);
        } else {
          float gg = __bfloat162float(aux[(size_t)r * N + c]);
          ((bf16*)Cp)[(size_t)r * N + c] = __float2bfloat16(v * gg);
        }
      }
    }
  }
}

// ============== MFMA flash attention, train self-attn (L=256) ==============
// Block per (seq n, head h); 4 waves x 64 q-rows; flash over 4 KV blocks of 64.
__global__ __launch_bounds__(256) void attn_t_m(
    const bf16* __restrict__ Q, const bf16* __restrict__ K,
    const bf16* __restrict__ V, bf16* __restrict__ O){
  __shared__ bf16 Klds[64][40];        // [key][d]   20-word stride: 2-way free
  __shared__ bf16 Vt[32][72];          // [d][key]   36-word stride: 2-way free
  __shared__ bf16 Plds[4][64][72];     // per-wave P tile [q][key]
  const int n = blockIdx.x, h = blockIdx.y;
  const int tid = threadIdx.x, lane = tid & 63, w = tid >> 6;
  const size_t hbase = (size_t)n * 256 * Dz + (size_t)h * 32;
  const int l15 = lane & 15, l4 = lane >> 4;
  short8v qf[4];
  #pragma unroll
  for (int m = 0; m < 4; ++m)
    qf[m] = *(const short8v*)(Q + hbase + (size_t)(w*64 + m*16 + l15) * Dz + l4*8);
  f32x4 accO[4][2] = {};
  float mrow[4][4], lrow[4][4];
  #pragma unroll
  for (int m=0;m<4;++m)
    #pragma unroll
    for (int j=0;j<4;++j){ mrow[m][j] = -1e30f; lrow[m][j] = 0.f; }
  const f32x4 zero = {};
  for (int kb = 0; kb < 4; ++kb){
    __syncthreads();
    {
      int r = tid >> 2, c8 = (tid & 3) * 8;
      *(uint4*)&Klds[r][c8] = *(const uint4*)(K + hbase + (size_t)(kb*64 + r) * Dz + c8);
      uint4 vr = *(const uint4*)(V + hbase + (size_t)(kb*64 + r) * Dz + c8);
      const bf16* vb = (const bf16*)&vr;
      #pragma unroll
      for (int i = 0; i < 8; ++i) Vt[c8 + i][r] = vb[i];
    }
    __syncthreads();
    short8v kf[4];
    #pragma unroll
    for (int nn = 0; nn < 4; ++nn)
      kf[nn] = *(const short8v*)&Klds[nn*16 + l15][l4*8];
    f32x4 s[4][4];
    #pragma unroll
    for (int m = 0; m < 4; ++m)
      #pragma unroll
      for (int nn = 0; nn < 4; ++nn)
        s[m][nn] = __builtin_amdgcn_mfma_f32_16x16x32_bf16(qf[m], kf[nn], zero, 0,0,0);
    #pragma unroll
    for (int m = 0; m < 4; ++m){
      #pragma unroll
      for (int j = 0; j < 4; ++j){
        float mx = fmaxf(fmaxf(s[m][0][j], s[m][1][j]), fmaxf(s[m][2][j], s[m][3][j]));
        mx = fmaxf(mx, __shfl_xor(mx, 1));
        mx = fmaxf(mx, __shfl_xor(mx, 2));
        mx = fmaxf(mx, __shfl_xor(mx, 4));
        mx = fmaxf(mx, __shfl_xor(mx, 8));
        float mnew = fmaxf(mrow[m][j], mx);
        float scl = __expf((mrow[m][j] - mnew) * SCALE);
        mrow[m][j] = mnew;
        float ps = 0.f;
        #pragma unroll
        for (int nn = 0; nn < 4; ++nn){
          float p = __expf((s[m][nn][j] - mnew) * SCALE);
          s[m][nn][j] = p; ps += p;
        }
        ps += __shfl_xor(ps, 1); ps += __shfl_xor(ps, 2);
        ps += __shfl_xor(ps, 4); ps += __shfl_xor(ps, 8);
        lrow[m][j] = lrow[m][j] * scl + ps;
        accO[m][0][j] *= scl; accO[m][1][j] *= scl;
      }
    }
    #pragma unroll
    for (int m = 0; m < 4; ++m)
      #pragma unroll
      for (int nn = 0; nn < 4; ++nn)
        #pragma unroll
        for (int j = 0; j < 4; ++j)
          Plds[w][m*16 + l4*4 + j][nn*16 + l15] = __float2bfloat16(s[m][nn][j]);
    #pragma unroll
    for (int m = 0; m < 4; ++m){
      #pragma unroll
      for (int kt = 0; kt < 2; ++kt){
        short8v pf = *(const short8v*)&Plds[w][m*16 + l15][kt*32 + l4*8];
        #pragma unroll
        for (int dt = 0; dt < 2; ++dt){
          short8v vf = *(const short8v*)&Vt[dt*16 + l15][kt*32 + l4*8];
          accO[m][dt] = __builtin_amdgcn_mfma_f32_16x16x32_bf16(pf, vf, accO[m][dt], 0,0,0);
        }
      }
    }
  }
  #pragma unroll
  for (int m = 0; m < 4; ++m){
    #pragma unroll
    for (int j = 0; j < 4; ++j){
      float inv = 1.0f / lrow[m][j];
      int row = w*64 + m*16 + l4*4 + j;
      #pragma unroll
      for (int dt = 0; dt < 2; ++dt)
        O[hbase + (size_t)row * Dz + dt*16 + l15] = __float2bfloat16(accO[m][dt][j] * inv);
    }
  }
}

// ============== MFMA flash attention, wave-per-(row,head) ==================
// NKB = #key blocks of 64 (1 = feature attn, 4 = cross attn).
// MASK = hybrid additive mask from global f32 mask (feature attn, heads 0-3).
template<int NKB, int MASK>
__global__ __launch_bounds__(256) void attn_w(
    const bf16* __restrict__ Q, const bf16* __restrict__ K,
    const bf16* __restrict__ V, const float* __restrict__ mask,
    bf16* __restrict__ O, int hb){
  __shared__ bf16 Klds[4][64][40];
  __shared__ bf16 Vt[4][32][72];
  __shared__ bf16 Plds[4][64][72];
  const int r = blockIdx.x;
  const int tid = threadIdx.x, lane = tid & 63, w = tid >> 6;
  const int h = hb + w;
  const int l15 = lane & 15, l4 = lane >> 4;
  const size_t qoff = (size_t)r * 64 * Dz + (size_t)h * 32;
  const size_t koff = (size_t)r * (NKB*64) * Dz + (size_t)h * 32;
  short8v qf[4];
  #pragma unroll
  for (int m = 0; m < 4; ++m)
    qf[m] = *(const short8v*)(Q + qoff + (size_t)(m*16 + l15) * Dz + l4*8);
  f32x4 accO[4][2] = {};
  float mrow[4][4], lrow[4][4];
  #pragma unroll
  for (int m=0;m<4;++m)
    #pragma unroll
    for (int j=0;j<4;++j){ mrow[m][j] = -1e30f; lrow[m][j] = 0.f; }
  const f32x4 zero = {};
  for (int kb = 0; kb < NKB; ++kb){
    {
      const bf16* kp = K + koff + (size_t)(kb*64 + lane) * Dz;
      const bf16* vp = V + koff + (size_t)(kb*64 + lane) * Dz;
      uint4 k0 = *(const uint4*)(kp);      uint4 k1 = *(const uint4*)(kp + 8);
      uint4 k2 = *(const uint4*)(kp + 16); uint4 k3 = *(const uint4*)(kp + 24);
      *(uint4*)&Klds[w][lane][0]  = k0; *(uint4*)&Klds[w][lane][8]  = k1;
      *(uint4*)&Klds[w][lane][16] = k2; *(uint4*)&Klds[w][lane][24] = k3;
      uint4 v0 = *(const uint4*)(vp);      uint4 v1 = *(const uint4*)(vp + 8);
      uint4 v2 = *(const uint4*)(vp + 16); uint4 v3 = *(const uint4*)(vp + 24);
      const bf16* vb0=(const bf16*)&v0; const bf16* vb1=(const bf16*)&v1;
      const bf16* vb2=(const bf16*)&v2; const bf16* vb3=(const bf16*)&v3;
      #pragma unroll
      for (int i = 0; i < 8; ++i){
        Vt[w][i][lane]      = vb0[i];
        Vt[w][8 + i][lane]  = vb1[i];
        Vt[w][16 + i][lane] = vb2[i];
        Vt[w][24 + i][lane] = vb3[i];
      }
    }
    short8v kf[4];
    #pragma unroll
    for (int nn = 0; nn < 4; ++nn)
      kf[nn] = *(const short8v*)&Klds[w][nn*16 + l15][l4*8];
    f32x4 s[4][4];
    #pragma unroll
    for (int m = 0; m < 4; ++m)
      #pragma unroll
      for (int nn = 0; nn < 4; ++nn)
        s[m][nn] = __builtin_amdgcn_mfma_f32_16x16x32_bf16(qf[m], kf[nn], zero, 0,0,0);
    if (MASK){
      #pragma unroll
      for (int m = 0; m < 4; ++m)
        #pragma unroll
        for (int nn = 0; nn < 4; ++nn)
          #pragma unroll
          for (int j = 0; j < 4; ++j){
            int row = m*16 + l4*4 + j, col = nn*16 + l15;
            s[m][nn][j] += (mask[row*64 + col] == 1.0f ? 0.0f : -1e30f);
          }
    }
    #pragma unroll
    for (int m = 0; m < 4; ++m){
      #pragma unroll
      for (int j = 0; j < 4; ++j){
        float mx = fmaxf(fmaxf(s[m][0][j], s[m][1][j]), fmaxf(s[m][2][j], s[m][3][j]));
        mx = fmaxf(mx, __shfl_xor(mx, 1));
        mx = fmaxf(mx, __shfl_xor(mx, 2));
        mx = fmaxf(mx, __shfl_xor(mx, 4));
        mx = fmaxf(mx, __shfl_xor(mx, 8));
        float mnew = fmaxf(mrow[m][j], mx);
        float scl = __expf((mrow[m][j] - mnew) * SCALE);
        mrow[m][j] = mnew;
        float ps = 0.f;
        #pragma unroll
        for (int nn = 0; nn < 4; ++nn){
          float p = __expf((s[m][nn][j] - mnew) * SCALE);
          s[m][nn][j] = p; ps += p;
        }
        ps += __shfl_xor(ps, 1); ps += __shfl_xor(ps, 2);
        ps += __shfl_xor(ps, 4); ps += __shfl_xor(ps, 8);
        lrow[m][j] = lrow[m][j] * scl + ps;
        accO[m][0][j] *= scl; accO[m][1][j] *= scl;
      }
    }
    #pragma unroll
    for (int m = 0; m < 4; ++m)
      #pragma unroll
      for (int nn = 0; nn < 4; ++nn)
        #pragma unroll
        for (int j = 0; j < 4; ++j)
          Plds[w][m*16 + l4*4 + j][nn*16 + l15] = __float2bfloat16(s[m][nn][j]);
    #pragma unroll
    for (int m = 0; m < 4; ++m){
      #pragma unroll
      for (int kt = 0; kt < 2; ++kt){
        short8v pf = *(const short8v*)&Plds[w][m*16 + l15][kt*32 + l4*8];
        #pragma unroll
        for (int dt = 0; dt < 2; ++dt){
          short8v vf = *(const short8v*)&Vt[w][dt*16 + l15][kt*32 + l4*8];
          accO[m][dt] = __builtin_amdgcn_mfma_f32_16x16x32_bf16(pf, vf, accO[m][dt], 0,0,0);
        }
      }
    }
  }
  #pragma unroll
  for (int m = 0; m < 4; ++m){
    #pragma unroll
    for (int j = 0; j < 4; ++j){
      float inv = 1.0f / lrow[m][j];
      int row = m*16 + l4*4 + j;
      #pragma unroll
      for (int dt = 0; dt < 2; ++dt)
        O[qoff + (size_t)row * Dz + dt*16 + l15] = __float2bfloat16(accO[m][dt][j] * inv);
    }
  }
}

// ---------------------------------------------------------------------------
extern "C" void kernel_launch(void* const* d_in, const int* in_sizes, int n_in,
                              void* d_out, int out_size, void* d_ws, size_t ws_size,
                              hipStream_t stream){
  (void)in_sizes; (void)n_in; (void)out_size; (void)ws_size;
  const float* x    = (const float*)d_in[0];
  const float* mask = (const float*)d_in[1];
  const float *Wqf=(const float*)d_in[2],  *Wkf=(const float*)d_in[3],
              *Wvf=(const float*)d_in[4],  *Wof=(const float*)d_in[5],
              *bqf=(const float*)d_in[6],  *bkf=(const float*)d_in[7],
              *bvf=(const float*)d_in[8],  *bof=(const float*)d_in[9],
              *gf =(const float*)d_in[10], *b2f=(const float*)d_in[11];
  const float *Wqt=(const float*)d_in[12], *Wkt=(const float*)d_in[13],
              *Wvt=(const float*)d_in[14], *Wot=(const float*)d_in[15],
              *bqt=(const float*)d_in[16], *bkt=(const float*)d_in[17],
              *bvt=(const float*)d_in[18], *bot=(const float*)d_in[19],
              *gt =(const float*)d_in[20], *b2t=(const float*)d_in[21];
  const float *Wqe=(const float*)d_in[22], *Wke=(const float*)d_in[23],
              *Wve=(const float*)d_in[24], *Woe=(const float*)d_in[25],
              *bqe=(const float*)d_in[26], *bke=(const float*)d_in[27],
              *bve=(const float*)d_in[28], *boe=(const float*)d_in[29],
              *ge =(const float*)d_in[30], *b2e=(const float*)d_in[31];
  const float *W1=(const float*)d_in[32], *b1=(const float*)d_in[33],
              *Wg=(const float*)d_in[34], *bg=(const float*)d_in[35],
              *W2=(const float*)d_in[36], *b2v=(const float*)d_in[37],
              *gm=(const float*)d_in[38], *bm=(const float*)d_in[39];

  float* Y = (float*)d_out;     // running activation in row layout (B,S,FN,D)

  char* wsb = (char*)d_ws;
  size_t off = 0;
  auto carve = [&](size_t bytes)->void*{
    void* p = wsb + off; off += (bytes + 255) & ~(size_t)255; return p;
  };
  bf16* Xn = (bf16*)carve((size_t)TOK * Dz * 2);   // LN'd activations (contiguous)
  bf16* Qb = (bf16*)carve((size_t)TOK * Dz * 2);
  bf16* Kb = (bf16*)carve((size_t)TOK * Dz * 2);
  bf16* Vb = (bf16*)carve((size_t)TOK * Dz * 2);
  bf16* Ob = (bf16*)carve((size_t)TOK * Dz * 2);
  // bf16 weights
  bf16 *wb[15];
  const float* wsrc[15] = {Wqf,Wkf,Wvf,Wof, Wqt,Wkt,Wvt,Wot, Wqe,Wke,Wve,Woe, W1,Wg,W2};
  const int    wn[15]   = {Dz*Dz,Dz*Dz,Dz*Dz,Dz*Dz, Dz*Dz,Dz*Dz,Dz*Dz,Dz*Dz,
                           Dz*Dz,Dz*Dz,Dz*Dz,Dz*Dz, HIDz*Dz,HIDz*Dz,HIDz*Dz};
  for (int i = 0; i < 15; ++i) wb[i] = (bf16*)carve((size_t)wn[i]*2);
  for (int i = 0; i < 15; ++i)
    cvt_kernel<<<wn[i]/1024, 256, 0, stream>>>(wsrc[i], wb[i], wn[i]);
  bf16 *Wqfb=wb[0],*Wkfb=wb[1],*Wvfb=wb[2],*Wofb=wb[3],
       *Wqtb=wb[4],*Wktb=wb[5],*Wvtb=wb[6],*Wotb=wb[7],
       *Wqeb=wb[8],*Wkeb=wb[9],*Wveb=wb[10],*Woeb=wb[11],
       *W1b=wb[12],*Wgb=wb[13],*W2b=wb[14];
  bf16* Gb = Qb;
  bf16* Hb = Vb;

  // ---------------- Stage A: feature attention ----------------
  ln_kernel<<<TOK/4, 256, 0, stream>>>(x, Xn, gf, b2f, 0, 0);
  mgemm<0><<<dim3(2, TOK/128), 256, 0, stream>>>(Xn, Wqfb, bqf, Qb, nullptr, nullptr, TOK, Dz, Dz, 0,0);
  mgemm<0><<<dim3(2, TOK/128), 256, 0, stream>>>(Xn, Wkfb, bkf, Kb, nullptr, nullptr, TOK, Dz, Dz, 0,0);
  mgemm<0><<<dim3(2, TOK/128), 256, 0, stream>>>(Xn, Wvfb, bvf, Vb, nullptr, nullptr, TOK, Dz, Dz, 0,0);
  attn_w<1,1><<<dim3(Bz*Sz), 256, 0, stream>>>(Qb, Kb, Vb, mask, Ob, 0);
  attn_w<1,0><<<dim3(Bz*Sz), 256, 0, stream>>>(Qb, Kb, Vb, nullptr, Ob, 4);
  mgemm<1><<<dim3(2, TOK/128), 256, 0, stream>>>(Ob, Wofb, bof, Y, x, nullptr, TOK, Dz, Dz, 0,0);

  // ---------------- Stage B: train self-attention ----------------
  ln_kernel<<<TTR/4, 256, 0, stream>>>(Y, Xn, gt, b2t, NTRz, 0);
  mgemm<0><<<dim3(2, TTR/128), 256, 0, stream>>>(Xn, Wqtb, bqt, Qb, nullptr, nullptr, TTR, Dz, Dz, 0,0);
  mgemm<0><<<dim3(2, TTR/128), 256, 0, stream>>>(Xn, Wktb, bkt, Kb, nullptr, nullptr, TTR, Dz, Dz, 0,0);
  mgemm<0><<<dim3(2, TTR/128), 256, 0, stream>>>(Xn, Wvtb, bvt, Vb, nullptr, nullptr, TTR, Dz, Dz, 0,0);
  attn_t_m<<<dim3(NSEQ, 8), 256, 0, stream>>>(Qb, Kb, Vb, Ob);
  mgemm<1><<<dim3(2, TTR/128), 256, 0, stream>>>(Ob, Wotb, bot, Y, Y, nullptr, TTR, Dz, Dz, NTRz,0);

  // ---------------- Stage C: cross attention ----------------
  ln_kernel<<<TTR/4, 256, 0, stream>>>(Y, Xn, ge, b2e, NTRz, 0);                 // kv rows
  ln_kernel<<<TTE/4, 256, 0, stream>>>(Y, Xn + (size_t)TTR*Dz, ge, b2e, NTEz, NTRz); // query rows
  mgemm<0><<<dim3(2, TTE/128), 256, 0, stream>>>(Xn + (size_t)TTR*Dz, Wqeb, bqe, Qb, nullptr, nullptr, TTE, Dz, Dz, 0,0);
  mgemm<0><<<dim3(2, TTR/128), 256, 0, stream>>>(Xn, Wkeb, bke, Kb, nullptr, nullptr, TTR, Dz, Dz, 0,0);
  mgemm<0><<<dim3(2, TTR/128), 256, 0, stream>>>(Xn, Wveb, bve, Vb, nullptr, nullptr, TTR, Dz, Dz, 0,0);
  attn_w<4,0><<<dim3(NSEQ), 256, 0, stream>>>(Qb, Kb, Vb, nullptr, Ob, 0);
  attn_w<4,0><<<dim3(NSEQ), 256, 0, stream>>>(Qb, Kb, Vb, nullptr, Ob, 4);
  mgemm<1><<<dim3(2, TTE/128), 256, 0, stream>>>(Ob, Woeb, boe, Y, Y, nullptr, TTE, Dz, Dz, NTEz,NTRz);

  // ---------------- Stage D: gated MLP ----------------
  ln_kernel<<<TOK/4, 256, 0, stream>>>(Y, Xn, gm, bm, 0, 0);
  for (int c = 0; c < TOK/16384; ++c){
    const bf16* Anc = Xn + (size_t)c * 16384 * Dz;
    float*      Yc  = Y  + (size_t)c * 16384 * Dz;
    mgemm<2><<<dim3(HIDz/128, 16384/128), 256, 0, stream>>>(Anc, Wgb, bg, Gb, nullptr, nullptr, 16384, HIDz, Dz, 0,0);
    mgemm<3><<<dim3(HIDz/128, 16384/128), 256, 0, stream>>>(Anc, W1b, b1, Hb, nullptr, Gb, 16384, HIDz, Dz, 0,0);
    mgemm<1><<<dim3(2, 16384/128), 256, 0, stream>>>(Hb, W2b, b2v, Yc, Yc, nullptr, 16384, Dz, HIDz, 0,0);
  }
}